// Round 12
// baseline (997.956 us; speedup 1.0000x reference)
//
#include <hip/hip_runtime.h>
#include <math.h>

// Problem constants (B=16, T=64, NN=4096, H=1024)
constexpr int kB = 16;
constexpr int kT = 64;
constexpr int kH = 1024;

typedef short bf16x8 __attribute__((ext_vector_type(8)));   // 8 bf16 = 4 VGPR
typedef float floatx4 __attribute__((ext_vector_type(4)));  // MFMA acc
typedef unsigned uintx4 __attribute__((ext_vector_type(4))); // 16B asm payload

// ---------------------------------------------------------------------------
// bf16 convert helpers
// ---------------------------------------------------------------------------
__device__ __forceinline__ unsigned short f2bf_rne(float f) {
    unsigned u = __float_as_uint(f);
    u = u + 0x7FFFu + ((u >> 16) & 1u);
    return (unsigned short)(u >> 16);
}
__device__ __forceinline__ unsigned f2bf_fast_u(float f) {
    return (__float_as_uint(f) + 0x8000u) >> 16;
}

// ---------------------------------------------------------------------------
// System-scope (coherence-point) ops — v4 proven. sc0 sc1 = "system" scope.
// (v6 lesson: sc0 alone is SE scope — NOT visible across the device.)
// ---------------------------------------------------------------------------
__device__ __forceinline__ void store_dword_sys(unsigned* p, unsigned v) {
    asm volatile("global_store_dword %0, %1, off sc0 sc1"
                 :: "v"(p), "v"(v) : "memory");
}
__device__ __forceinline__ unsigned load_dword_sys(const unsigned* p) {
    unsigned v;
    asm volatile("global_load_dword %0, %1, off sc0 sc1\n\t"
                 "s_waitcnt vmcnt(0)"
                 : "=v"(v) : "v"(p) : "memory");
    return v;
}
// non-waiting 16B sys load (poll path batches the waitcnt)
__device__ __forceinline__ uintx4 load_x4_sys(const unsigned* p) {
    uintx4 v;
    asm volatile("global_load_dwordx4 %0, %1, off sc0 sc1"
                 : "=&v"(v) : "v"(p) : "memory");
    return v;
}
// 3 independent sys-loads, one waitcnt (gx0 prefetch path)
__device__ __forceinline__ void load3_float_sys(const float* p0, const float* p1,
                                                const float* p2,
                                                float& a, float& b, float& c) {
    asm volatile("global_load_dword %0, %3, off sc0 sc1\n\t"
                 "global_load_dword %1, %4, off sc0 sc1\n\t"
                 "global_load_dword %2, %5, off sc0 sc1\n\t"
                 "s_waitcnt vmcnt(0)"
                 : "=&v"(a), "=&v"(b), "=&v"(c)
                 : "v"(p0), "v"(p1), "v"(p2) : "memory");
}

// async global->LDS, 16 B per lane (wave-uniform LDS base, per-lane src)
__device__ __forceinline__ void gload_lds16(const unsigned short* g,
                                            unsigned short* lds) {
    __builtin_amdgcn_global_load_lds(
        (const __attribute__((address_space(1))) unsigned int*)(g),
        (__attribute__((address_space(3))) unsigned int*)(lds), 16, 0, 0);
}

// ---------------------------------------------------------------------------
// Merged pack kernel: 5 fp32->bf16 (RNE) jobs in one launch.
// ---------------------------------------------------------------------------
__global__ __launch_bounds__(256)
void pack_bf16_multi(const float* __restrict__ s0, unsigned short* __restrict__ d0, int n0,
                     const float* __restrict__ s1, unsigned short* __restrict__ d1, int n1,
                     const float* __restrict__ s2, unsigned short* __restrict__ d2, int n2,
                     const float* __restrict__ s3, unsigned short* __restrict__ d3, int n3,
                     const float* __restrict__ s4, unsigned short* __restrict__ d4, int n4)
{
    int i = blockIdx.x * 256 + threadIdx.x;
    const float* s; unsigned short* d;
    if (i < n0) { s = s0; d = d0; }
    else { i -= n0;
    if (i < n1) { s = s1; d = d1; }
    else { i -= n1;
    if (i < n2) { s = s2; d = d2; }
    else { i -= n2;
    if (i < n3) { s = s3; d = d3; }
    else { i -= n3;
    if (i >= n4) return; s = s4; d = d4; }}}}
    const float4 v = ((const float4*)s)[i];
    ushort4 o;
    o.x = f2bf_rne(v.x); o.y = f2bf_rne(v.y);
    o.z = f2bf_rne(v.z); o.w = f2bf_rne(v.w);
    ((ushort4*)d)[i] = o;
}

// ---------------------------------------------------------------------------
// 64x64-tile fp32 GEMM (decoder only; M=16 guard): C = X@W^T + bias
// ---------------------------------------------------------------------------
#define GBM 64
#define GBN 64
#define GBK 16
#define GPAD 4

__global__ __launch_bounds__(256)
void gemm_nt_bias(const float* __restrict__ X, const float* __restrict__ W,
                  const float* __restrict__ bias, float* __restrict__ C,
                  int M, int N, int K)
{
    __shared__ float Xs[GBK][GBM + GPAD];
    __shared__ float Ws[GBK][GBN + GPAD];

    const int tid = threadIdx.x;
    const int bm = blockIdx.y * GBM;
    const int bn = blockIdx.x * GBN;
    const int tm = (tid >> 4) * 4;
    const int tn = (tid & 15) * 4;
    const int lr = tid >> 2;
    const int lc = (tid & 3) * 4;

    float acc[4][4] = {};

    for (int k0 = 0; k0 < K; k0 += GBK) {
        {
            const int gr = bm + lr;
            float4 v = make_float4(0.f, 0.f, 0.f, 0.f);
            if (gr < M) v = *(const float4*)(X + (long)gr * K + k0 + lc);
            Xs[lc + 0][lr] = v.x; Xs[lc + 1][lr] = v.y;
            Xs[lc + 2][lr] = v.z; Xs[lc + 3][lr] = v.w;
        }
        {
            const int gr = bn + lr;
            const float4 v = *(const float4*)(W + (long)gr * K + k0 + lc);
            Ws[lc + 0][lr] = v.x; Ws[lc + 1][lr] = v.y;
            Ws[lc + 2][lr] = v.z; Ws[lc + 3][lr] = v.w;
        }
        __syncthreads();
        #pragma unroll
        for (int k = 0; k < GBK; ++k) {
            const float4 a4 = *(const float4*)&Xs[k][tm];
            const float4 b4 = *(const float4*)&Ws[k][tn];
            acc[0][0] += a4.x * b4.x; acc[0][1] += a4.x * b4.y; acc[0][2] += a4.x * b4.z; acc[0][3] += a4.x * b4.w;
            acc[1][0] += a4.y * b4.x; acc[1][1] += a4.y * b4.y; acc[1][2] += a4.y * b4.z; acc[1][3] += a4.y * b4.w;
            acc[2][0] += a4.z * b4.x; acc[2][1] += a4.z * b4.y; acc[2][2] += a4.z * b4.z; acc[2][3] += a4.z * b4.w;
            acc[3][0] += a4.w * b4.x; acc[3][1] += a4.w * b4.y; acc[3][2] += a4.w * b4.z; acc[3][3] += a4.w * b4.w;
        }
        __syncthreads();
    }

    #pragma unroll
    for (int i = 0; i < 4; ++i) {
        const int gr = bm + tm + i;
        if (gr >= M) continue;
        #pragma unroll
        for (int jj = 0; jj < 4; ++jj) {
            const int gc = bn + tn + jj;
            C[(long)gr * N + gc] = acc[i][jj] + bias[gc];
        }
    }
}

// ---------------------------------------------------------------------------
// MEGA-KERNEL v8: recurrence (blocks 0..63) + Phase-A GEMM workers
// (blocks 64..255) in one launch — now with TAG-IN-DATA h exchange and
// NO grid barrier.
//
// h is published as u32 = (bf16 << 16) | gen, gen = write-step+1. Both h1
// and h2 consumers at step k expect gen == k exactly. Consumers poll-load
// their actual A-fragments (16x dwordx4 sc0 sc1 per wave) and retry until
// all tags match. This removes the v4 chain's producer vmcnt-ack, flag
// store, and detect->load round trips (~2 of 4-5 L3 RTs per step).
// WAR safety on the ping-pong: a block writes gen k+2 only after reading
// (= confirming written) all of gen k+1, which implies every block has
// finished READING gen k — writes of step j's outputs prove reads of step
// j's inputs. Stale tags across graph replays are killed by a 256 KB
// memset (equality check + zeroed tags). Poll timeout -> visible absmax
// failure, never a hang.
// ---------------------------------------------------------------------------
#define POLL_TIMEOUT 20000000LL

__global__ __launch_bounds__(768, 2)
void fused_mega(const unsigned short* __restrict__ xbf,    // [1024,4096] bf16
                const unsigned short* __restrict__ wihbf,  // [3072,4096] bf16
                const float* __restrict__ bih0,            // [3072]
                float* __restrict__ gx0,                   // [1024,3072]
                const unsigned short* __restrict__ w0, const float* __restrict__ bb0,
                const unsigned short* __restrict__ w1, const float* __restrict__ bb1,
                const unsigned short* __restrict__ w2, const float* __restrict__ bb2,
                unsigned* __restrict__ h1t0, unsigned* __restrict__ h1t1,
                unsigned* __restrict__ h2t0, unsigned* __restrict__ h2t1,
                float* __restrict__ h2last, unsigned* __restrict__ flags)
{
    __shared__ __attribute__((aligned(16))) char smem[49152];  // union, 48 KB

    const int tid = threadIdx.x;     // 0..767
    const int bx  = blockIdx.x;
    const int lane = tid & 63;
    const int wid  = tid >> 6;       // 0..11
    unsigned* const gxflags = flags + 256;   // 384 uints: [chunk*24 + ntile]

    if (bx >= 64) {
        // =================== GEMM WORKER (unchanged from v7) ===============
        unsigned short (*As)[2048] = (unsigned short(*)[2048])smem;            // [4][64*32]
        unsigned short (*Bs)[4096] = (unsigned short(*)[4096])(smem + 16384);  // [4][128*32]
        const int widx = bx - 64;            // 0..191
        const int srow = lane >> 2;          // 0..15
        const int scol = (lane & 3) * 8;     // 0,8,16,24
        const int al = lane & 15;
        const int aq = lane >> 4;
        const int wm = wid & 1;              // MFMA waves (wid<8): 32-row half
        const int wn = wid >> 1;             // 0..3: 32-col quarter

        for (int pass = 0; pass < 2; ++pass) {
            const int T = widx + pass * 192;     // 0..383
            const int c = T / 24;                // t-chunk 0..15
            const int n = T % 24;                // N-tile
            const int bn = n * 128;

            const unsigned short* gsrc;
            int ldsoff;
            bool isA;
            if (wid < 4) {
                const int tr = wid * 16 + srow;
                const long grow = (long)((tr >> 2) * 64 + c * 4 + (tr & 3));
                gsrc = xbf + grow * 4096 + scol;
                ldsoff = wid * 512;
                isA = true;
            } else {
                gsrc = wihbf + (long)(bn + (wid - 4) * 16 + srow) * 4096 + scol;
                ldsoff = (wid - 4) * 512;
                isA = false;
            }

            floatx4 acc[2][2];
            #pragma unroll
            for (int i = 0; i < 2; ++i)
                #pragma unroll
                for (int j = 0; j < 2; ++j)
                    acc[i][j] = (floatx4){0.f, 0.f, 0.f, 0.f};

            if (isA) { gload_lds16(gsrc + 0,  &As[0][ldsoff]);
                       gload_lds16(gsrc + 32, &As[1][ldsoff]); }
            else     { gload_lds16(gsrc + 0,  &Bs[0][ldsoff]);
                       gload_lds16(gsrc + 32, &Bs[1][ldsoff]); }

            for (int t = 0; t < 128; ++t) {
                const int k2 = (t + 2 < 128) ? (t + 2) * 32 : t * 32;
                const int b2 = (t + 2) & 3;
                if (isA) gload_lds16(gsrc + k2, &As[b2][ldsoff]);
                else     gload_lds16(gsrc + k2, &Bs[b2][ldsoff]);

                asm volatile("s_waitcnt vmcnt(2)" ::: "memory");
                __builtin_amdgcn_s_barrier();
                asm volatile("" ::: "memory");

                if (wid < 8) {
                    const int cb = t & 3;
                    bf16x8 af[2], bfr[2];
                    #pragma unroll
                    for (int i = 0; i < 2; ++i)
                        af[i] = *(const bf16x8*)&As[cb][(wm * 32 + i * 16 + al) * 32 + aq * 8];
                    #pragma unroll
                    for (int j = 0; j < 2; ++j)
                        bfr[j] = *(const bf16x8*)&Bs[cb][(wn * 32 + j * 16 + al) * 32 + aq * 8];
                    #pragma unroll
                    for (int i = 0; i < 2; ++i)
                        #pragma unroll
                        for (int j = 0; j < 2; ++j)
                            acc[i][j] = __builtin_amdgcn_mfma_f32_16x16x32_bf16(
                                af[i], bfr[j], acc[i][j], 0, 0, 0);
                }
                asm volatile("" ::: "memory");
                __builtin_amdgcn_s_barrier();
            }

            if (wid < 8) {
                #pragma unroll
                for (int i = 0; i < 2; ++i) {
                    #pragma unroll
                    for (int j = 0; j < 2; ++j) {
                        const int col = bn + wn * 32 + j * 16 + al;
                        const float bv = bih0[col];
                        #pragma unroll
                        for (int r = 0; r < 4; ++r) {
                            const int tr = wm * 32 + i * 16 + aq * 4 + r;
                            const long g = (long)((tr >> 2) * 64 + c * 4 + (tr & 3));
                            store_dword_sys((unsigned*)&gx0[g * 3072 + col],
                                            __float_as_uint(acc[i][j][r] + bv));
                        }
                    }
                }
            }
            asm volatile("s_waitcnt vmcnt(0)" ::: "memory");
            __builtin_amdgcn_s_barrier();
            if (tid == 0) store_dword_sys(&gxflags[c * 24 + n], 1u);
        }
        return;
    }

    // =================== RECURRENCE (tag-in-data, barrier-free) ============
    floatx4 (*part)[3][64] = (floatx4(*)[3][64])smem;   // [12][3][64], 36 KB

    const int jbase = bx * 16;
    const int ntile = bx >> 3;         // gx0 N-tile covering our 16 cols

    const int m  = wid >> 2;           // matrix: 0 w_hh0, 1 w_ih1, 2 w_hh1
    const int kh = wid & 3;            // K-quarter
    const int al = lane & 15;
    const int aq = lane >> 4;

    // ---- one-time: weight fragments -> registers ----
    const unsigned short* Wm = (m == 0) ? w0 : (m == 1) ? w1 : w2;
    const long wbase = (long)(jbase + al) * kH + kh * 256 + aq * 8;
    bf16x8 wreg[3][8];
    #pragma unroll
    for (int g = 0; g < 3; ++g)
        #pragma unroll
        for (int s = 0; s < 8; ++s)
            wreg[g][s] = *(const bf16x8*)(Wm + (long)g * kH * kH + wbase + s * 32);

    // ---- one-time: update-phase bias preload (tid<256 only) ----
    const int ub  = tid >> 4;          // batch row for update phase
    const int ujj = tid & 15;
    const int ujg = jbase + ujj;
    const float b0r = bb0[ujg], b0z = bb0[kH + ujg], b0n = bb0[2 * kH + ujg];
    const float b1r = bb1[ujg], b1z = bb1[kH + ujg], b1n = bb1[2 * kH + ujg];
    const float b2r = bb2[ujg], b2z = bb2[kH + ujg], b2n = bb2[2 * kH + ujg];

    float h1reg = 0.f;   // h1_{k-1} for this (b,j)
    float h2reg = 0.f;   // h2_{k-2} for this (b,j)

    // A-fragment offset in tagged u32 h buffers
    const unsigned aoff = al * kH + kh * 256 + aq * 8;
    const int pl   = (ub >> 2) * 16 + ujj;
    const int pr   = ub & 3;

    // gx0 for step 0: gate on chunk 0, then sys-load
    float gxr = 0.f, gxz = 0.f, gxn = 0.f;
    int readyChunk = -1;
    if (tid < 256) {
        while (load_dword_sys(&gxflags[0 * 24 + ntile]) == 0) {}
        readyChunk = 0;
        const float* g = gx0 + (long)ub * (kT * 3 * kH);
        load3_float_sys(g + ujg, g + kH + ujg, g + 2 * kH + ujg, gxr, gxz, gxn);
    }

    for (int k = 0; k <= kT; ++k) {
        // ping-pong pointers (tagged u32 buffers; same parity map as v4)
        const unsigned* h1p = (k & 1) ? h1t0 : h1t1;   // h1_{k-1}, tag k
        unsigned*       h1o = (k & 1) ? h1t1 : h1t0;   // h1_k, tag k+1
        const unsigned* h2p = (k & 1) ? h2t1 : h2t0;   // h2_{k-2}, tag k
        unsigned*       h2o = (k & 1) ? h2t0 : h2t1;   // h2_{k-1}, tag k+1

        // ---- A-fragments: tagged poll-load (THE synchronization) ----
        const bool azero = (m < 2) ? (k == 0) : (k <= 1);
        const unsigned* hsrc = ((m < 2) ? h1p : h2p) + aoff;
        bf16x8 a[8];
        if (!azero) {
            const unsigned expg = (unsigned)k;
            uintx4 t0[8], t1[8];
            const long long tstart = clock64();
            for (;;) {
                #pragma unroll
                for (int s = 0; s < 8; ++s) {
                    t0[s] = load_x4_sys(hsrc + s * 32);
                    t1[s] = load_x4_sys(hsrc + s * 32 + 4);
                }
                asm volatile("s_waitcnt vmcnt(0)" ::: "memory");
                __builtin_amdgcn_sched_barrier(0);
                bool ok = true;
                #pragma unroll
                for (int s = 0; s < 8; ++s) {
                    ok &= ((t0[s].x & 0xFFFFu) == expg) & ((t0[s].y & 0xFFFFu) == expg)
                        & ((t0[s].z & 0xFFFFu) == expg) & ((t0[s].w & 0xFFFFu) == expg);
                    ok &= ((t1[s].x & 0xFFFFu) == expg) & ((t1[s].y & 0xFFFFu) == expg)
                        & ((t1[s].z & 0xFFFFu) == expg) & ((t1[s].w & 0xFFFFu) == expg);
                }
                if (__all(ok)) break;
                if (clock64() - tstart > POLL_TIMEOUT) break;  // fail visibly
            }
            #pragma unroll
            for (int s = 0; s < 8; ++s) {
                a[s][0] = (short)(t0[s].x >> 16);
                a[s][1] = (short)(t0[s].y >> 16);
                a[s][2] = (short)(t0[s].z >> 16);
                a[s][3] = (short)(t0[s].w >> 16);
                a[s][4] = (short)(t1[s].x >> 16);
                a[s][5] = (short)(t1[s].y >> 16);
                a[s][6] = (short)(t1[s].z >> 16);
                a[s][7] = (short)(t1[s].w >> 16);
            }
        } else {
            #pragma unroll
            for (int s = 0; s < 8; ++s)
                a[s] = (bf16x8){0, 0, 0, 0, 0, 0, 0, 0};
        }

        // ---- 24 MFMAs (weights + A in registers) ----
        floatx4 acc[3];
        #pragma unroll
        for (int g = 0; g < 3; ++g) acc[g] = (floatx4){0.f, 0.f, 0.f, 0.f};
        #pragma unroll
        for (int s = 0; s < 8; ++s)
            #pragma unroll
            for (int g = 0; g < 3; ++g)
                acc[g] = __builtin_amdgcn_mfma_f32_16x16x32_bf16(
                    a[s], wreg[g][s], acc[g], 0, 0, 0);

        #pragma unroll
        for (int g = 0; g < 3; ++g)
            part[wid][g][lane] = acc[g];     // ds_write_b128, conflict-free
        __syncthreads();

        // ---- cell updates (256 threads: b = tid>>4, j = tid&15) ----
        if (tid < 256) {
            float gh[3][3];
            #pragma unroll
            for (int mm = 0; mm < 3; ++mm)
                #pragma unroll
                for (int g = 0; g < 3; ++g)
                    gh[mm][g] = part[mm * 4 + 0][g][pl][pr] + part[mm * 4 + 1][g][pl][pr]
                              + part[mm * 4 + 2][g][pl][pr] + part[mm * 4 + 3][g][pl][pr];

            const unsigned wtag = (unsigned)(k + 1);
            if (k < kT) {   // layer0 step t=k
                const float hr = gh[0][0] + b0r;
                const float hz = gh[0][1] + b0z;
                const float hn = gh[0][2] + b0n;
                const float r = 1.f / (1.f + __expf(-(gxr + hr)));
                const float z = 1.f / (1.f + __expf(-(gxz + hz)));
                const float n = tanhf(gxn + r * hn);
                const float hnew = (1.f - z) * n + z * h1reg;
                h1reg = hnew;
                store_dword_sys(h1o + ub * kH + ujg,
                                (f2bf_fast_u(hnew) << 16) | wtag);   // fire & forget
            }
            if (k > 0) {    // layer1 step t=k-1; gx1 = gh[1] + b_ih1
                const float xr = gh[1][0] + b1r;
                const float xz = gh[1][1] + b1z;
                const float xn = gh[1][2] + b1n;
                const float hr = gh[2][0] + b2r;
                const float hz = gh[2][1] + b2z;
                const float hn = gh[2][2] + b2n;
                const float r = 1.f / (1.f + __expf(-(xr + hr)));
                const float z = 1.f / (1.f + __expf(-(xz + hz)));
                const float n = tanhf(xn + r * hn);
                const float hnew = (1.f - z) * n + z * h2reg;
                h2reg = hnew;
                store_dword_sys(h2o + ub * kH + ujg,
                                (f2bf_fast_u(hnew) << 16) | wtag);
                if (k == kT) h2last[(long)ub * kH + ujg] = hnew;  // fp32 for decoder
            }
        }

        // ---- prefetch gx0 for step k+1 (gated per chunk) ----
        float nxr = 0.f, nxz = 0.f, nxn = 0.f;
        if (tid < 256 && (k + 1) < kT) {
            const int c2 = (k + 1) >> 2;
            if (c2 != readyChunk) {
                while (load_dword_sys(&gxflags[c2 * 24 + ntile]) == 0) {}
                readyChunk = c2;
            }
            const float* g = gx0 + (long)ub * (kT * 3 * kH) + (long)(k + 1) * 3 * kH;
            load3_float_sys(g + ujg, g + kH + ujg, g + 2 * kH + ujg, nxr, nxz, nxn);
        }

        __syncthreads();   // part WAR: update reads done before next writes

        gxr = nxr; gxz = nxz; gxn = nxn;
    }
}

// ---------------------------------------------------------------------------
// kernel_launch
// ---------------------------------------------------------------------------
extern "C" void kernel_launch(void* const* d_in, const int* in_sizes, int n_in,
                              void* d_out, int out_size, void* d_ws, size_t ws_size,
                              hipStream_t stream)
{
    const float* x        = (const float*)d_in[0];   // [16,64,4096]
    const float* w_ih_l0  = (const float*)d_in[1];   // [3072,4096]
    const float* w_hh_l0  = (const float*)d_in[2];   // [3072,1024]
    const float* b_ih_l0  = (const float*)d_in[3];   // [3072]
    const float* b_hh_l0  = (const float*)d_in[4];   // [3072]
    const float* w_ih_l1  = (const float*)d_in[5];   // [3072,1024]
    const float* w_hh_l1  = (const float*)d_in[6];   // [3072,1024]
    const float* b_ih_l1  = (const float*)d_in[7];   // [3072]
    const float* b_hh_l1  = (const float*)d_in[8];   // [3072]
    const float* dec_w    = (const float*)d_in[9];   // [4096,1024]
    const float* dec_b    = (const float*)d_in[10];  // [4096]
    float* out = (float*)d_out;                      // [16,4096]

    // Workspace (~63 MB): gx0 12 MB + 4 tagged h-bufs 256 KB + h2last 64 KB
    // + 3 recurrence bf16 matrices 18 MB + xbf 8 MB + wihbf 24 MB + flags.
    float* ws    = (float*)d_ws;
    float* gx0   = ws;                                  // [1024,3072] rows b*T+t
    unsigned* h1t0 = (unsigned*)(gx0 + (size_t)1024 * 3072);
    unsigned* h1t1 = h1t0 + (size_t)kB * kH;
    unsigned* h2t0 = h1t1 + (size_t)kB * kH;
    unsigned* h2t1 = h2t0 + (size_t)kB * kH;
    float* h2last = (float*)(h2t1 + (size_t)kB * kH);
    unsigned short* wbf0 = (unsigned short*)(h2last + (size_t)kB * kH);
    unsigned short* wbf1 = wbf0 + (size_t)3 * kH * kH;
    unsigned short* wbf2 = wbf1 + (size_t)3 * kH * kH;
    unsigned short* xbf  = wbf2 + (size_t)3 * kH * kH;          // [1024,4096]
    unsigned short* wihbf = xbf + (size_t)1024 * 4096;          // [3072,4096]
    unsigned* flags = (unsigned*)(wihbf + (size_t)3072 * 4096);

    // Tagged h buffers (gen=0) + flags must start zeroed each replay.
    (void)hipMemsetAsync(h1t0, 0, 4 * (size_t)kB * kH * sizeof(unsigned), stream);
    (void)hipMemsetAsync(flags, 0, 4096, stream);

    const int wn4 = 3 * kH * kH / 4;           // 786432
    const int xn4 = 1024 * 4096 / 4;           // 1048576
    const int win4 = 3072 * 4096 / 4;          // 3145728
    const int total4 = wn4 * 3 + xn4 + win4;   // 6553600

    // ONE merged pack launch (5 jobs)
    pack_bf16_multi<<<(total4 + 255) / 256, 256, 0, stream>>>(
        w_hh_l0, wbf0, wn4,  w_ih_l1, wbf1, wn4,  w_hh_l1, wbf2, wn4,
        x, xbf, xn4,  w_ih_l0, wihbf, win4);

    // MEGA: Phase-A workers (192 blocks) + barrier-free tagged recurrence
    // (64 blocks). Single launch.
    fused_mega<<<256, 768, 0, stream>>>(
        xbf, wihbf, b_ih_l0, gx0,
        wbf0, b_hh_l0, wbf1, b_ih_l1, wbf2, b_hh_l1,
        h1t0, h1t1, h2t0, h2t1, h2last, flags);

    // Decoder (fp32): out = h2_last @ dec_w^T + dec_b  (M=16,N=4096,K=1024)
    gemm_nt_bias<<<dim3(4096 / GBN, 1), 256, 0, stream>>>(
        h2last, dec_w, dec_b, out, kB, 4096, 1024);
}

// Round 15
// 607.960 us; speedup vs baseline: 1.6415x; 1.6415x over previous
//
#include <hip/hip_runtime.h>
#include <math.h>

// Problem constants (B=16, T=64, NN=4096, H=1024)
constexpr int kB = 16;
constexpr int kT = 64;
constexpr int kH = 1024;

typedef short bf16x8 __attribute__((ext_vector_type(8)));   // 8 bf16 = 4 VGPR
typedef float floatx4 __attribute__((ext_vector_type(4)));  // MFMA acc

// ---------------------------------------------------------------------------
// bf16 convert helpers
// ---------------------------------------------------------------------------
__device__ __forceinline__ unsigned short f2bf_rne(float f) {
    unsigned u = __float_as_uint(f);
    u = u + 0x7FFFu + ((u >> 16) & 1u);
    return (unsigned short)(u >> 16);
}
__device__ __forceinline__ unsigned f2bf_fast_u(float f) {
    return (__float_as_uint(f) + 0x8000u) >> 16;
}

// ---------------------------------------------------------------------------
// System-scope (coherence-point) ops — v4 proven. sc0 sc1 = "system" scope.
// (v6: sc0 alone = SE scope. v8: tag-in-data re-poll loses to flag chain.
//  v9/v10: in-flight loads across raw s_barrier + in-kernel decoder
//  crashed — REVERTED; this version holds no VMEM state across barriers.)
// ---------------------------------------------------------------------------
__device__ __forceinline__ void store_short_sys(unsigned short* p, unsigned v) {
    asm volatile("global_store_short %0, %1, off sc0 sc1"
                 :: "v"(p), "v"(v) : "memory");
}
__device__ __forceinline__ void store_dword_sys(unsigned* p, unsigned v) {
    asm volatile("global_store_dword %0, %1, off sc0 sc1"
                 :: "v"(p), "v"(v) : "memory");
}
__device__ __forceinline__ unsigned load_dword_sys(const unsigned* p) {
    unsigned v;
    asm volatile("global_load_dword %0, %1, off sc0 sc1\n\t"
                 "s_waitcnt vmcnt(0)"
                 : "=v"(v) : "v"(p) : "memory");
    return v;
}
// blocking 3-load (prologue only)
__device__ __forceinline__ void load3_float_sys(const float* p0, const float* p1,
                                                const float* p2,
                                                float& a, float& b, float& c) {
    asm volatile("global_load_dword %0, %3, off sc0 sc1\n\t"
                 "global_load_dword %1, %4, off sc0 sc1\n\t"
                 "global_load_dword %2, %5, off sc0 sc1\n\t"
                 "s_waitcnt vmcnt(0)"
                 : "=&v"(a), "=&v"(b), "=&v"(c)
                 : "v"(p0), "v"(p1), "v"(p2) : "memory");
}
// ISSUE-ONLY 3-load: joined with the A-fragment loads under ONE vmcnt(0)
// in the SAME code region (no barrier crossed while in flight).
__device__ __forceinline__ void issue3_float_sys(const float* p0, const float* p1,
                                                 const float* p2,
                                                 float& a, float& b, float& c) {
    asm volatile("global_load_dword %0, %3, off sc0 sc1\n\t"
                 "global_load_dword %1, %4, off sc0 sc1\n\t"
                 "global_load_dword %2, %5, off sc0 sc1"
                 : "=&v"(a), "=&v"(b), "=&v"(c)
                 : "v"(p0), "v"(p1), "v"(p2) : "memory");
}

// async global->LDS, 16 B per lane (wave-uniform LDS base, per-lane src)
__device__ __forceinline__ void gload_lds16(const unsigned short* g,
                                            unsigned short* lds) {
    __builtin_amdgcn_global_load_lds(
        (const __attribute__((address_space(1))) unsigned int*)(g),
        (__attribute__((address_space(3))) unsigned int*)(lds), 16, 0, 0);
}

// ---------------------------------------------------------------------------
// Merged pack kernel: 5 fp32->bf16 (RNE) jobs in one launch.
// ---------------------------------------------------------------------------
__global__ __launch_bounds__(256)
void pack_bf16_multi(const float* __restrict__ s0, unsigned short* __restrict__ d0, int n0,
                     const float* __restrict__ s1, unsigned short* __restrict__ d1, int n1,
                     const float* __restrict__ s2, unsigned short* __restrict__ d2, int n2,
                     const float* __restrict__ s3, unsigned short* __restrict__ d3, int n3,
                     const float* __restrict__ s4, unsigned short* __restrict__ d4, int n4)
{
    int i = blockIdx.x * 256 + threadIdx.x;
    const float* s; unsigned short* d;
    if (i < n0) { s = s0; d = d0; }
    else { i -= n0;
    if (i < n1) { s = s1; d = d1; }
    else { i -= n1;
    if (i < n2) { s = s2; d = d2; }
    else { i -= n2;
    if (i < n3) { s = s3; d = d3; }
    else { i -= n3;
    if (i >= n4) return; s = s4; d = d4; }}}}
    const float4 v = ((const float4*)s)[i];
    ushort4 o;
    o.x = f2bf_rne(v.x); o.y = f2bf_rne(v.y);
    o.z = f2bf_rne(v.z); o.w = f2bf_rne(v.w);
    ((ushort4*)d)[i] = o;
}

// ---------------------------------------------------------------------------
// 64x64-tile fp32 GEMM (decoder only; M=16 guard): C = X@W^T + bias
// ---------------------------------------------------------------------------
#define GBM 64
#define GBN 64
#define GBK 16
#define GPAD 4

__global__ __launch_bounds__(256)
void gemm_nt_bias(const float* __restrict__ X, const float* __restrict__ W,
                  const float* __restrict__ bias, float* __restrict__ C,
                  int M, int N, int K)
{
    __shared__ float Xs[GBK][GBM + GPAD];
    __shared__ float Ws[GBK][GBN + GPAD];

    const int tid = threadIdx.x;
    const int bm = blockIdx.y * GBM;
    const int bn = blockIdx.x * GBN;
    const int tm = (tid >> 4) * 4;
    const int tn = (tid & 15) * 4;
    const int lr = tid >> 2;
    const int lc = (tid & 3) * 4;

    float acc[4][4] = {};

    for (int k0 = 0; k0 < K; k0 += GBK) {
        {
            const int gr = bm + lr;
            float4 v = make_float4(0.f, 0.f, 0.f, 0.f);
            if (gr < M) v = *(const float4*)(X + (long)gr * K + k0 + lc);
            Xs[lc + 0][lr] = v.x; Xs[lc + 1][lr] = v.y;
            Xs[lc + 2][lr] = v.z; Xs[lc + 3][lr] = v.w;
        }
        {
            const int gr = bn + lr;
            const float4 v = *(const float4*)(W + (long)gr * K + k0 + lc);
            Ws[lc + 0][lr] = v.x; Ws[lc + 1][lr] = v.y;
            Ws[lc + 2][lr] = v.z; Ws[lc + 3][lr] = v.w;
        }
        __syncthreads();
        #pragma unroll
        for (int k = 0; k < GBK; ++k) {
            const float4 a4 = *(const float4*)&Xs[k][tm];
            const float4 b4 = *(const float4*)&Ws[k][tn];
            acc[0][0] += a4.x * b4.x; acc[0][1] += a4.x * b4.y; acc[0][2] += a4.x * b4.z; acc[0][3] += a4.x * b4.w;
            acc[1][0] += a4.y * b4.x; acc[1][1] += a4.y * b4.y; acc[1][2] += a4.y * b4.z; acc[1][3] += a4.y * b4.w;
            acc[2][0] += a4.z * b4.x; acc[2][1] += a4.z * b4.y; acc[2][2] += a4.z * b4.z; acc[2][3] += a4.z * b4.w;
            acc[3][0] += a4.w * b4.x; acc[3][1] += a4.w * b4.y; acc[3][2] += a4.w * b4.z; acc[3][3] += a4.w * b4.w;
        }
        __syncthreads();
    }

    #pragma unroll
    for (int i = 0; i < 4; ++i) {
        const int gr = bm + tm + i;
        if (gr >= M) continue;
        #pragma unroll
        for (int jj = 0; jj < 4; ++jj) {
            const int gc = bn + tn + jj;
            C[(long)gr * N + gc] = acc[i][jj] + bias[gc];
        }
    }
}

// ---------------------------------------------------------------------------
// MEGA-KERNEL v11 (= proven v7 + one change): recurrence (blocks 0..63,
// v4 flag chain, __syncthreads barriers) + Phase-A GEMM workers (64..255).
//
// vs v7 (mega 425us): the blocking gx0 sys-load is moved from the update
// phase into the A-FRAGMENT ISSUE GROUP of the same step — 3 extra dwords
// issued alongside the 8 dwordx4s, covered by the SAME s_waitcnt vmcnt(0).
// The gx0 round trip rides the A-load round trip (zero extra serial RTs).
// The chunk-readiness gate (1-dword poll, almost always already set) stays
// in the update phase of the PREVIOUS step. No VMEM state crosses any
// barrier (the v9/v10 crash pattern is gone).
// ---------------------------------------------------------------------------
#define FLAG_STRIDE 4   // uints; 16 B between recurrence flags

__global__ __launch_bounds__(768, 2)
void fused_mega(const unsigned short* __restrict__ xbf,    // [1024,4096] bf16
                const unsigned short* __restrict__ wihbf,  // [3072,4096] bf16
                const float* __restrict__ bih0,            // [3072]
                float* __restrict__ gx0,                   // [1024,3072]
                const unsigned short* __restrict__ w0, const float* __restrict__ bb0,
                const unsigned short* __restrict__ w1, const float* __restrict__ bb1,
                const unsigned short* __restrict__ w2, const float* __restrict__ bb2,
                unsigned short* __restrict__ h1bf0, unsigned short* __restrict__ h1bf1,
                unsigned short* __restrict__ h2bf0, unsigned short* __restrict__ h2bf1,
                float* __restrict__ h2last, unsigned* __restrict__ flags)
{
    __shared__ __attribute__((aligned(16))) char smem[49152];  // union, 48 KB

    const int tid = threadIdx.x;     // 0..767
    const int bx  = blockIdx.x;
    const int lane = tid & 63;
    const int wid  = tid >> 6;       // 0..11
    unsigned* const gxflags = flags + 256;   // 384 uints: [chunk*24 + ntile]

    if (bx >= 64) {
        // =================== GEMM WORKER (v7 verbatim) =====================
        unsigned short (*As)[2048] = (unsigned short(*)[2048])smem;            // [4][64*32]
        unsigned short (*Bs)[4096] = (unsigned short(*)[4096])(smem + 16384);  // [4][128*32]
        const int widx = bx - 64;            // 0..191
        const int srow = lane >> 2;          // 0..15
        const int scol = (lane & 3) * 8;     // 0,8,16,24
        const int al = lane & 15;
        const int aq = lane >> 4;
        const int wm = wid & 1;              // MFMA waves (wid<8): 32-row half
        const int wn = wid >> 1;             // 0..3: 32-col quarter

        for (int pass = 0; pass < 2; ++pass) {
            const int T = widx + pass * 192;     // 0..383
            const int c = T / 24;                // t-chunk 0..15
            const int n = T % 24;                // N-tile
            const int bn = n * 128;

            const unsigned short* gsrc;
            int ldsoff;
            bool isA;
            if (wid < 4) {
                const int tr = wid * 16 + srow;
                const long grow = (long)((tr >> 2) * 64 + c * 4 + (tr & 3));
                gsrc = xbf + grow * 4096 + scol;
                ldsoff = wid * 512;
                isA = true;
            } else {
                gsrc = wihbf + (long)(bn + (wid - 4) * 16 + srow) * 4096 + scol;
                ldsoff = (wid - 4) * 512;
                isA = false;
            }

            floatx4 acc[2][2];
            #pragma unroll
            for (int i = 0; i < 2; ++i)
                #pragma unroll
                for (int j = 0; j < 2; ++j)
                    acc[i][j] = (floatx4){0.f, 0.f, 0.f, 0.f};

            if (isA) { gload_lds16(gsrc + 0,  &As[0][ldsoff]);
                       gload_lds16(gsrc + 32, &As[1][ldsoff]); }
            else     { gload_lds16(gsrc + 0,  &Bs[0][ldsoff]);
                       gload_lds16(gsrc + 32, &Bs[1][ldsoff]); }

            for (int t = 0; t < 128; ++t) {
                const int k2 = (t + 2 < 128) ? (t + 2) * 32 : t * 32;
                const int b2 = (t + 2) & 3;
                if (isA) gload_lds16(gsrc + k2, &As[b2][ldsoff]);
                else     gload_lds16(gsrc + k2, &Bs[b2][ldsoff]);

                asm volatile("s_waitcnt vmcnt(2)" ::: "memory");
                __builtin_amdgcn_s_barrier();
                asm volatile("" ::: "memory");

                if (wid < 8) {
                    const int cb = t & 3;
                    bf16x8 af[2], bfr[2];
                    #pragma unroll
                    for (int i = 0; i < 2; ++i)
                        af[i] = *(const bf16x8*)&As[cb][(wm * 32 + i * 16 + al) * 32 + aq * 8];
                    #pragma unroll
                    for (int j = 0; j < 2; ++j)
                        bfr[j] = *(const bf16x8*)&Bs[cb][(wn * 32 + j * 16 + al) * 32 + aq * 8];
                    #pragma unroll
                    for (int i = 0; i < 2; ++i)
                        #pragma unroll
                        for (int j = 0; j < 2; ++j)
                            acc[i][j] = __builtin_amdgcn_mfma_f32_16x16x32_bf16(
                                af[i], bfr[j], acc[i][j], 0, 0, 0);
                }
                asm volatile("" ::: "memory");
                __builtin_amdgcn_s_barrier();
            }

            if (wid < 8) {
                #pragma unroll
                for (int i = 0; i < 2; ++i) {
                    #pragma unroll
                    for (int j = 0; j < 2; ++j) {
                        const int col = bn + wn * 32 + j * 16 + al;
                        const float bv = bih0[col];
                        #pragma unroll
                        for (int r = 0; r < 4; ++r) {
                            const int tr = wm * 32 + i * 16 + aq * 4 + r;
                            const long g = (long)((tr >> 2) * 64 + c * 4 + (tr & 3));
                            store_dword_sys((unsigned*)&gx0[g * 3072 + col],
                                            __float_as_uint(acc[i][j][r] + bv));
                        }
                    }
                }
            }
            asm volatile("s_waitcnt vmcnt(0)" ::: "memory");
            __builtin_amdgcn_s_barrier();
            if (tid == 0) store_dword_sys(&gxflags[c * 24 + n], 1u);
        }
        return;
    }

    // =================== RECURRENCE (v7 + gx0-in-A-group) ==================
    floatx4 (*part)[3][64] = (floatx4(*)[3][64])smem;   // [12][3][64], 36 KB

    const int jbase = bx * 16;
    const int ntile = bx >> 3;         // gx0 N-tile covering our 16 cols

    const int m  = wid >> 2;           // matrix: 0 w_hh0, 1 w_ih1, 2 w_hh1
    const int kh = wid & 3;            // K-quarter
    const int al = lane & 15;
    const int aq = lane >> 4;

    // ---- one-time: weight fragments -> registers ----
    const unsigned short* Wm = (m == 0) ? w0 : (m == 1) ? w1 : w2;
    const long wbase = (long)(jbase + al) * kH + kh * 256 + aq * 8;
    bf16x8 wreg[3][8];
    #pragma unroll
    for (int g = 0; g < 3; ++g)
        #pragma unroll
        for (int s = 0; s < 8; ++s)
            wreg[g][s] = *(const bf16x8*)(Wm + (long)g * kH * kH + wbase + s * 32);

    // ---- one-time: update-phase bias preload (tid<256 only) ----
    const int ub  = tid >> 4;          // batch row for update phase
    const int ujj = tid & 15;
    const int ujg = jbase + ujj;
    const float b0r = bb0[ujg], b0z = bb0[kH + ujg], b0n = bb0[2 * kH + ujg];
    const float b1r = bb1[ujg], b1z = bb1[kH + ujg], b1n = bb1[2 * kH + ujg];
    const float b2r = bb2[ujg], b2z = bb2[kH + ujg], b2n = bb2[2 * kH + ujg];

    float h1reg = 0.f;   // h1_{k-1} for this (b,j)
    float h2reg = 0.f;   // h2_{k-2} for this (b,j)

    const int aoff = al * kH + kh * 256 + aq * 8;
    const int pl   = (ub >> 2) * 16 + ujj;
    const int pr   = ub & 3;

    // gx0 for step 0: gate on chunk 0, then blocking load (once)
    float gxr = 0.f, gxz = 0.f, gxn = 0.f;
    int readyChunk = -1;
    if (tid < 256) {
        while (load_dword_sys(&gxflags[0 * 24 + ntile]) == 0) {}
        readyChunk = 0;
        const float* g = gx0 + (long)ub * (kT * 3 * kH);
        load3_float_sys(g + ujg, g + kH + ujg, g + 2 * kH + ujg, gxr, gxz, gxn);
    }

    for (int k = 0; k <= kT; ++k) {
        const unsigned short* h1p = (k & 1) ? h1bf0 : h1bf1;   // h1_{k-1}
        unsigned short*       h1o = (k & 1) ? h1bf1 : h1bf0;   // h1_k
        const unsigned short* h2p = (k & 1) ? h2bf1 : h2bf0;   // h2_{k-2}
        unsigned short*       h2o = (k & 1) ? h2bf0 : h2bf1;   // h2_{k-1}

        // ---- A-phase issue group: gx0 for THIS step + A-fragments,
        //      ONE vmcnt(0) covers all (gx0 RT rides the A-load RT) ----
        if (tid < 256 && k >= 1 && k < kT) {
            // chunk(k) readiness was verified in update phase of step k-1
            const float* g = gx0 + (long)ub * (kT * 3 * kH) + (long)k * 3 * kH;
            issue3_float_sys(g + ujg, g + kH + ujg, g + 2 * kH + ujg,
                             gxr, gxz, gxn);
        }
        const bool azero = (m < 2) ? (k == 0) : (k <= 1);
        const unsigned short* hsrc = (m < 2) ? h1p : h2p;
        bf16x8 a[8];
        if (!azero) {
            #pragma unroll
            for (int s = 0; s < 8; ++s)
                asm volatile("global_load_dwordx4 %0, %1, off sc0 sc1"
                             : "=&v"(a[s]) : "v"(hsrc + aoff + s * 32) : "memory");
        } else {
            #pragma unroll
            for (int s = 0; s < 8; ++s)
                a[s] = (bf16x8){0, 0, 0, 0, 0, 0, 0, 0};
        }
        asm volatile("s_waitcnt vmcnt(0)" ::: "memory");
        __builtin_amdgcn_sched_barrier(0);

        // ---- 24 MFMAs (weights + A in registers) ----
        floatx4 acc[3];
        #pragma unroll
        for (int g = 0; g < 3; ++g) acc[g] = (floatx4){0.f, 0.f, 0.f, 0.f};
        #pragma unroll
        for (int s = 0; s < 8; ++s)
            #pragma unroll
            for (int g = 0; g < 3; ++g)
                acc[g] = __builtin_amdgcn_mfma_f32_16x16x32_bf16(
                    a[s], wreg[g][s], acc[g], 0, 0, 0);

        #pragma unroll
        for (int g = 0; g < 3; ++g)
            part[wid][g][lane] = acc[g];     // ds_write_b128, conflict-free
        __syncthreads();

        // ---- cell updates (256 threads: b = tid>>4, j = tid&15) ----
        if (tid < 256) {
            float gh[3][3];
            #pragma unroll
            for (int mm = 0; mm < 3; ++mm)
                #pragma unroll
                for (int g = 0; g < 3; ++g)
                    gh[mm][g] = part[mm * 4 + 0][g][pl][pr] + part[mm * 4 + 1][g][pl][pr]
                              + part[mm * 4 + 2][g][pl][pr] + part[mm * 4 + 3][g][pl][pr];

            if (k < kT) {   // layer0 step t=k
                const float hr = gh[0][0] + b0r;
                const float hz = gh[0][1] + b0z;
                const float hn = gh[0][2] + b0n;
                const float r = 1.f / (1.f + __expf(-(gxr + hr)));
                const float z = 1.f / (1.f + __expf(-(gxz + hz)));
                const float n = tanhf(gxn + r * hn);
                const float hnew = (1.f - z) * n + z * h1reg;
                h1reg = hnew;
                store_short_sys(h1o + ub * kH + ujg, f2bf_fast_u(hnew));
            }
            if (k > 0) {    // layer1 step t=k-1; gx1 = gh[1] + b_ih1
                const float xr = gh[1][0] + b1r;
                const float xz = gh[1][1] + b1z;
                const float xn = gh[1][2] + b1n;
                const float hr = gh[2][0] + b2r;
                const float hz = gh[2][1] + b2z;
                const float hn = gh[2][2] + b2n;
                const float r = 1.f / (1.f + __expf(-(xr + hr)));
                const float z = 1.f / (1.f + __expf(-(xz + hz)));
                const float n = tanhf(xn + r * hn);
                const float hnew = (1.f - z) * n + z * h2reg;
                h2reg = hnew;
                store_short_sys(h2o + ub * kH + ujg, f2bf_fast_u(hnew));
                if (k == kT) h2last[(long)ub * kH + ujg] = hnew;  // fp32 for decoder
            }

            // readiness gate for chunk(k+1) ONLY (no data load here)
            if ((k + 1) < kT) {
                const int c2 = (k + 1) >> 2;
                if (c2 != readyChunk) {
                    while (load_dword_sys(&gxflags[c2 * 24 + ntile]) == 0) {}
                    readyChunk = c2;
                }
            }
        }

        // ---- distributed-flag all-poll barrier (v4/v7, proven) ----
        if (k < kT) {
            __syncthreads();          // per-wave vmcnt(0): sc-stores ACKed at L3
            if (wid == 0) {
                const unsigned gen = (unsigned)(k + 1);
                if (lane == 0)
                    store_dword_sys(&flags[bx * FLAG_STRIDE], gen);
                while (load_dword_sys(&flags[lane * FLAG_STRIDE]) < gen) {}
            }
            __syncthreads();
        }
    }
}

// ---------------------------------------------------------------------------
// kernel_launch
// ---------------------------------------------------------------------------
extern "C" void kernel_launch(void* const* d_in, const int* in_sizes, int n_in,
                              void* d_out, int out_size, void* d_ws, size_t ws_size,
                              hipStream_t stream)
{
    const float* x        = (const float*)d_in[0];   // [16,64,4096]
    const float* w_ih_l0  = (const float*)d_in[1];   // [3072,4096]
    const float* w_hh_l0  = (const float*)d_in[2];   // [3072,1024]
    const float* b_ih_l0  = (const float*)d_in[3];   // [3072]
    const float* b_hh_l0  = (const float*)d_in[4];   // [3072]
    const float* w_ih_l1  = (const float*)d_in[5];   // [3072,1024]
    const float* w_hh_l1  = (const float*)d_in[6];   // [3072,1024]
    const float* b_ih_l1  = (const float*)d_in[7];   // [3072]
    const float* b_hh_l1  = (const float*)d_in[8];   // [3072]
    const float* dec_w    = (const float*)d_in[9];   // [4096,1024]
    const float* dec_b    = (const float*)d_in[10];  // [4096]
    float* out = (float*)d_out;                      // [16,4096]

    // Workspace (~62.5 MB): gx0 12 MB + 4 bf16 h-bufs 128 KB + h2last 64 KB
    // + 3 recurrence bf16 matrices 18 MB + xbf 8 MB + wihbf 24 MB + flags.
    float* ws    = (float*)d_ws;
    float* gx0   = ws;                                  // [1024,3072] rows b*T+t
    unsigned short* h1bf0 = (unsigned short*)(gx0 + (size_t)1024 * 3072);
    unsigned short* h1bf1 = h1bf0 + (size_t)kB * kH;
    unsigned short* h2bf0 = h1bf1 + (size_t)kB * kH;
    unsigned short* h2bf1 = h2bf0 + (size_t)kB * kH;
    float* h2last = (float*)(h2bf1 + (size_t)kB * kH);
    unsigned short* wbf0 = (unsigned short*)(h2last + (size_t)kB * kH);
    unsigned short* wbf1 = wbf0 + (size_t)3 * kH * kH;
    unsigned short* wbf2 = wbf1 + (size_t)3 * kH * kH;
    unsigned short* xbf  = wbf2 + (size_t)3 * kH * kH;          // [1024,4096]
    unsigned short* wihbf = xbf + (size_t)1024 * 4096;          // [3072,4096]
    unsigned* flags = (unsigned*)(wihbf + (size_t)3072 * 4096);

    // flags[0..255]: recurrence barrier; flags[256..639]: gx0 tile flags.
    (void)hipMemsetAsync(flags, 0, 4096, stream);

    const int wn4 = 3 * kH * kH / 4;           // 786432
    const int xn4 = 1024 * 4096 / 4;           // 1048576
    const int win4 = 3072 * 4096 / 4;          // 3145728
    const int total4 = wn4 * 3 + xn4 + win4;   // 6553600

    // ONE merged pack launch (5 jobs)
    pack_bf16_multi<<<(total4 + 255) / 256, 256, 0, stream>>>(
        w_hh_l0, wbf0, wn4,  w_ih_l1, wbf1, wn4,  w_hh_l1, wbf2, wn4,
        x, xbf, xn4,  w_ih_l0, wihbf, win4);

    // MEGA: Phase-A workers (192 blocks) overlapped with the persistent
    // recurrence (64 blocks). Single launch.
    fused_mega<<<256, 768, 0, stream>>>(
        xbf, wihbf, b_ih_l0, gx0,
        wbf0, b_hh_l0, wbf1, b_ih_l1, wbf2, b_hh_l1,
        h1bf0, h1bf1, h2bf0, h2bf1, h2last, flags);

    // Decoder (fp32): out = h2_last @ dec_w^T + dec_b  (M=16,N=4096,K=1024)
    gemm_nt_bias<<<dim3(4096 / GBN, 1), 256, 0, stream>>>(
        h2last, dec_w, dec_b, out, kB, 4096, 1024);
}